// Round 9
// baseline (278.912 us; speedup 1.0000x reference)
//
#include <hip/hip_runtime.h>
#include <hip/hip_bf16.h>
#include <math.h>

// CBiAFormerBlock fused implementation, round 21.
// Post-mortem r20 (276.3us, WIN): NT stores + no-swizzle = correct gather
// config; attn2 back to ~46us (issue-bound: VALU 52%, occ 31%, HBM 20%).
// Non-attn family ~192us remains unprofiled (top-5 = 1 kernel x 5 replays).
// r21 (safe bundle):
//  - mgemm: BN template param.  QKV + MLP1 -> 128x128 tile (m92->m93 ladder
//    step: +51% on this exact 2-barrier structure), proj -> 64x128.
//    mlp2 (OUTM=1 transpose epilogue) + offgrid unchanged at BN=64.
//  - attn2: PE bias via paired aligned ds_read_b32 (r17-proven mapping;
//    halves scattered LDS ops, conflict-free lanes) + s_setprio(1) around
//    both MFMA clusters (guide: +4-7% attn, independent-phase blocks).
// All else byte-identical to r20.

typedef __hip_bfloat16 bf16;
typedef __bf16 bf16x8 __attribute__((ext_vector_type(8)));
typedef float f32x4 __attribute__((ext_vector_type(4)));
typedef unsigned int u32x4 __attribute__((ext_vector_type(4)));

union U16x8 { uint4 u4; u32x4 v4; unsigned short us[8]; };
union FU { float f; unsigned int u; };

__device__ __forceinline__ float cvt(float x) { return x; }
__device__ __forceinline__ float cvt(bf16 x) { return __bfloat162float(x); }
__device__ __forceinline__ float b2f(unsigned short u) {
  union { float f; unsigned int v; } x; x.v = ((unsigned int)u) << 16; return x.f;
}
__device__ __forceinline__ float hi2f(unsigned int u) {
  FU x; x.u = u & 0xffff0000u; return x.f;
}
__device__ __forceinline__ float lo2f(unsigned int u) {
  FU x; x.u = u << 16; return x.f;
}
__device__ __forceinline__ unsigned short f2b(float f) {
  bf16 h = __float2bfloat16(f);
  return *reinterpret_cast<unsigned short*>(&h);
}
__device__ __forceinline__ float gelu_f(float x) {
  return 0.5f * x * (1.0f + erff(x * 0.7071067811865475f));
}
__device__ __forceinline__ void stout(float* p, float v) { *p = v; }
__device__ __forceinline__ void stout(bf16* p, float v) { *p = __float2bfloat16(v); }

// ---------------- setup: LN1 (blocks 0..255) UNION weight prep (256..4355) --
__global__ __launch_bounds__(256) void setup_kernel(
    const float* __restrict__ x, const float* __restrict__ g,
    const float* __restrict__ bta,
    const float* __restrict__ q_w, const float* __restrict__ q_b,
    const float* __restrict__ k_w, const float* __restrict__ v_w,
    const float* __restrict__ pjw, const float* __restrict__ w1,
    const float* __restrict__ w2, const float* __restrict__ off4w,
    bf16* __restrict__ out, float* __restrict__ xnhwc,
    unsigned short* __restrict__ wqkv, float* __restrict__ bqkv,
    unsigned short* __restrict__ wproj, unsigned short* __restrict__ wmlp1,
    unsigned short* __restrict__ wmlp2, unsigned short* __restrict__ woff4i)
{
  __shared__ float s1[8][32], s2[8][32];
  __shared__ unsigned short tb[32][264];
  int bid = blockIdx.x;
  int t = threadIdx.x;
  if (bid < 256) {
    int pos = t & 31, cs = t >> 5;
    int p = bid * 32 + pos;
    int bb = p >> 12, hw = p & 4095;
    const float* xp = x + (size_t)bb * 256 * 4096 + hw;
    float vloc[32];
    float sum = 0.f, ss = 0.f;
#pragma unroll
    for (int i = 0; i < 32; ++i) {
      float v = xp[(size_t)(cs * 32 + i) * 4096];
      vloc[i] = v; sum += v; ss += v * v;
    }
    s1[cs][pos] = sum; s2[cs][pos] = ss;
    {
      float* xo = xnhwc + (size_t)p * 256 + cs * 32;
#pragma unroll
      for (int qd = 0; qd < 8; ++qd)
        *(float4*)(xo + qd * 4) = make_float4(vloc[qd*4], vloc[qd*4+1],
                                              vloc[qd*4+2], vloc[qd*4+3]);
    }
    __syncthreads();
    if (cs == 0) {
      float S = 0.f, Q = 0.f;
#pragma unroll
      for (int i = 0; i < 8; ++i) { S += s1[i][pos]; Q += s2[i][pos]; }
      float mu = S * (1.f / 256.f);
      float var = Q * (1.f / 256.f) - mu * mu;
      s1[0][pos] = mu;
      s2[0][pos] = rsqrtf(var + 1e-5f);
    }
    __syncthreads();
    float mu = s1[0][pos], rs = s2[0][pos];
#pragma unroll
    for (int i = 0; i < 32; ++i) {
      int c = cs * 32 + i;
      tb[pos][c] = f2b((vloc[i] - mu) * rs * g[c] + bta[c]);
    }
    __syncthreads();
    int px = t >> 3, grp = t & 7;
    bf16* op = out + ((size_t)bid * 32 + px) * 256 + grp * 32;
#pragma unroll
    for (int q = 0; q < 4; ++q)
      *(uint4*)(op + q * 8) = *(const uint4*)&tb[px][grp * 32 + q * 8];
  } else {
    int idx = (bid - 256) * 256 + t;
    const int S0 = 768 * 256;          // q|K|V weights, dezeroed
    const int S1 = S0 + 768;           // bias
    const int S2 = S1 + 256 * 256;
    const int S3 = S2 + 1024 * 256;
    const int S4 = S3 + 256 * 1024;
    const int S5 = S4 + 2048 * 128;
    if (idx < S0) {
      int n = idx >> 8, c = idx & 255;
      float v;
      if (n < 256)       v = q_w[n * 256 + c];
      else if (n < 512)  v = k_w[(n - 256) * 256 + c];
      else               v = v_w[(n - 512) * 256 + c];
      wqkv[idx] = f2b(v);
    } else if (idx < S1) {
      int n = idx - S0;
      bqkv[n] = (n < 256) ? q_b[n] : 0.f;
    } else if (idx < S2) {
      wproj[idx - S1] = f2b(pjw[idx - S1]);
    } else if (idx < S3) {
      wmlp1[idx - S2] = f2b(w1[idx - S2]);
    } else if (idx < S4) {
      wmlp2[idx - S3] = f2b(w2[idx - S3]);
    } else if (idx < S5) {
      int kk = idx - S4;
      int n = kk >> 7, c = kk & 127;
      // interleaved: n = 2r + coord  <-  off4w row coord*1024 + r
      woff4i[kk] = f2b(off4w[((size_t)((n & 1) * 1024 + (n >> 1))) * 128 + c]);
    }
  }
}

// ---------------- LN2: NHWC bf16 in -> NHWC bf16 out -----------------------
__global__ __launch_bounds__(256) void ln2_kernel(
    const bf16* __restrict__ xin, const float* __restrict__ g,
    const float* __restrict__ bta, bf16* __restrict__ out)
{
  __shared__ float sa[8][32], sb[8][32];
  __shared__ float mu_s[32], rs_s[32];
  int t = threadIdx.x;
  int px = t >> 3, grp = t & 7;
  size_t p = (size_t)blockIdx.x * 32 + px;
  const bf16* xp = xin + p * 256 + grp * 32;
  float v[32]; float sum = 0.f, ss = 0.f;
#pragma unroll
  for (int q = 0; q < 4; ++q) {
    U16x8 u; u.u4 = *(const uint4*)(xp + q * 8);
#pragma unroll
    for (int j = 0; j < 8; ++j) {
      float f = b2f(u.us[j]); v[q * 8 + j] = f; sum += f; ss += f * f;
    }
  }
  sa[grp][px] = sum; sb[grp][px] = ss;
  __syncthreads();
  if (t < 32) {
    float S = 0.f, Q = 0.f;
#pragma unroll
    for (int i = 0; i < 8; ++i) { S += sa[i][t]; Q += sb[i][t]; }
    float mu = S * (1.f / 256.f);
    mu_s[t] = mu;
    rs_s[t] = rsqrtf(Q * (1.f / 256.f) - mu * mu + 1e-5f);
  }
  __syncthreads();
  float mu = mu_s[px], rs = rs_s[px];
  bf16* op = out + p * 256 + grp * 32;
#pragma unroll
  for (int q = 0; q < 4; ++q) {
    U16x8 o;
#pragma unroll
    for (int j = 0; j < 8; ++j) {
      int c = grp * 32 + q * 8 + j;
      o.us[j] = f2b((v[q * 8 + j] - mu) * rs * g[c] + bta[c]);
    }
    *(uint4*)(op + q * 8) = o.u4;
  }
}

// ---------------- MFMA GEMM (NHWC): out[p][o] = sum_c A[p][c] W[o][c] ------
// OUTM: 0 bf16 NHWC; 1 f32 NCHW via LDS transpose (BN=64 only); 4 grouped-
//       QKV; 5 offset-grid head + coord pack (out=goff, res=gwt).
// RESM: 0 none; 1 f32 NHWC; 2 bf16 NHWC. ACT: 1 exact GELU.
// r21: BN template param; block tile BM x BN, 4 waves in 2x2.
template<int OUTM, int RESM, int ACT, int BM, int BN>
__global__ __launch_bounds__(256) void mgemm_kernel(
    const bf16* __restrict__ A, const unsigned short* __restrict__ Bw,
    const float* __restrict__ bias, const void* __restrict__ res,
    void* __restrict__ out, int N, int K, int lda, int ldb)
{
  constexpr int MT = BM / 32;
  constexpr int WNT = BN / 32;
  constexpr int AB_BYTES = (BM + BN) * 72 * 2;
  constexpr int T_LD = BM + 5;
  constexpr int T_BYTES = 64 * T_LD * 4;
  constexpr int SH_BYTES = (OUTM == 1 && T_BYTES > AB_BYTES) ? T_BYTES : AB_BYTES;
  __shared__ __attribute__((aligned(16))) char shraw[SH_BYTES];
  auto As = reinterpret_cast<unsigned short(*)[72]>(shraw);
  auto Bs = reinterpret_cast<unsigned short(*)[72]>(shraw + BM * 72 * 2);
  float (*T)[T_LD] = reinterpret_cast<float(*)[T_LD]>(shraw);

  int t = threadIdx.x;
  int m0 = blockIdx.y * BM, n0 = blockIdx.x * BN;
  int lane = t & 63, w = t >> 6;
  int l15 = lane & 15, quad = lane >> 4;
  int wm = (w >> 1) * (BM / 2), wn = (w & 1) * (BN / 2);
  f32x4 acc[MT][WNT];
#pragma unroll
  for (int mt = 0; mt < MT; ++mt)
#pragma unroll
    for (int nt = 0; nt < WNT; ++nt) acc[mt][nt] = (f32x4){0.f, 0.f, 0.f, 0.f};

  for (int k0 = 0; k0 < K; k0 += 64) {
#pragma unroll
    for (int i = 0; i < MT; ++i) {
      int idx = t + i * 256;
      int m = idx >> 3, oc = (idx & 7) * 8;
      *(uint4*)&As[m][oc] = *(const uint4*)(A + (size_t)(m0 + m) * lda + k0 + oc);
    }
#pragma unroll
    for (int i = 0; i < WNT; ++i) {
      int idx = t + i * 256;
      int n = idx >> 3, oc = (idx & 7) * 8;
      *(uint4*)&Bs[n][oc] = *(const uint4*)(Bw + (size_t)(n0 + n) * ldb + k0 + oc);
    }
    __syncthreads();
#pragma unroll
    for (int ks = 0; ks < 2; ++ks) {
      bf16x8 af[MT], bfr[WNT];
#pragma unroll
      for (int mt = 0; mt < MT; ++mt)
        af[mt] = __builtin_bit_cast(bf16x8,
            *(const uint4*)&As[wm + mt * 16 + l15][ks * 32 + quad * 8]);
#pragma unroll
      for (int nt = 0; nt < WNT; ++nt)
        bfr[nt] = __builtin_bit_cast(bf16x8,
            *(const uint4*)&Bs[wn + nt * 16 + l15][ks * 32 + quad * 8]);
#pragma unroll
      for (int mt = 0; mt < MT; ++mt)
#pragma unroll
        for (int nt = 0; nt < WNT; ++nt)
          acc[mt][nt] = __builtin_amdgcn_mfma_f32_16x16x32_bf16(
              af[mt], bfr[nt], acc[mt][nt], 0, 0, 0);
    }
    __syncthreads();
  }
  float bv[WNT];
#pragma unroll
  for (int nt = 0; nt < WNT; ++nt)
    bv[nt] = bias ? bias[n0 + wn + nt * 16 + l15] : 0.f;
#pragma unroll
  for (int mt = 0; mt < MT; ++mt) {
#pragma unroll
    for (int nt = 0; nt < WNT; ++nt) {
#pragma unroll
      for (int reg = 0; reg < 4; ++reg) {
        int m = m0 + wm + mt * 16 + quad * 4 + reg;
        int n = n0 + wn + nt * 16 + l15;
        float v = acc[mt][nt][reg] + bv[nt];
        if constexpr (ACT == 1) v = gelu_f(v);
        if constexpr (RESM == 1)
          v += ((const float*)res)[(size_t)m * N + n];
        if constexpr (RESM == 2)
          v += b2f(((const unsigned short*)res)[(size_t)m * N + n]);
        if constexpr (OUTM == 0)
          ((unsigned short*)out)[(size_t)m * N + n] = f2b(v);
        if constexpr (OUTM == 1)
          T[(n - n0)][(m - m0)] = v;
        if constexpr (OUTM == 4)
          ((unsigned short*)out)[((size_t)(n >> 8) * 8192 + m) * 256 + (n & 255)] = f2b(v);
        if constexpr (OUTM == 5) {
          float val = tanhf(v) * (2.0f / 64.0f);
          int r = n >> 1, coord = n & 1;
          int rc = coord ? (r & 31) : (r >> 5);
          float ref = rc * (4.0f / 63.0f) - 1.0f;
          float pix = (val + ref + 1.0f) * 31.5f;
          float other = __shfl_xor(pix, 1, 64);
          if (coord == 0) {
            float rowp = pix, colp = other;
            float r0f = floorf(rowp), c0f = floorf(colp);
            float wr = rowp - r0f, wc = colp - c0f;
            int r0 = (int)r0f, c0 = (int)c0f;
            bool rv0 = ((unsigned)r0 < 64u), rv1 = ((unsigned)(r0 + 1) < 64u);
            bool cv0 = ((unsigned)c0 < 64u), cv1 = ((unsigned)(c0 + 1) < 64u);
            float4 w4;
            w4.x = (rv0 && cv0) ? (1.f - wr) * (1.f - wc) : 0.f;
            w4.y = (rv0 && cv1) ? (1.f - wr) * wc : 0.f;
            w4.z = (rv1 && cv0) ? wr * (1.f - wc) : 0.f;
            w4.w = (rv1 && cv1) ? wr * wc : 0.f;
            ((int*)out)[(size_t)m * 1024 + r] = r0 * 64 + c0;
            *(float4*)((float*)res + ((size_t)m * 1024 + r) * 4) = w4;
          }
        }
      }
    }
  }
  if constexpr (OUTM == 1) {
    __syncthreads();
    constexpr int SEGS = BM / 32;
    int units = 64 * SEGS;
    if (t < units) {
      int nl = t / SEGS, seg = t % SEGS;
      int bI = m0 >> 12, hw0 = m0 & 4095;
      float* op = (float*)out + ((size_t)bI * 256 + n0 + nl) * 4096 + hw0 + seg * 32;
#pragma unroll
      for (int k = 0; k < 32; ++k) op[k] = T[nl][seg * 32 + k];
    }
  }
}

// ---------------- depthwise 3x3 stride-2 pad-1 conv, NHWC-128 --------------
template<typename TI, typename TO, int IC>
__global__ __launch_bounds__(256) void dwconv_kernel(
    const TI* __restrict__ in, const float* __restrict__ wgt,
    TO* __restrict__ out, int Hi, int Wi, int Ho, int Wo, int fuse,
    const float* __restrict__ bg_, const float* __restrict__ bb_,
    const float* __restrict__ bm_, const float* __restrict__ bv_)
{
  int idx = blockIdx.x * 256 + threadIdx.x;
  int c = idx & 127;
  int pp = idx >> 7;
  int ow = pp % Wo, oh = (pp / Wo) % Ho, bgi = pp / (Wo * Ho);
  const TI* ip;
  if constexpr (IC == 256)
    ip = in + ((size_t)(bgi >> 1) * 4096) * 256 + (bgi & 1) * 128 + c;
  else
    ip = in + ((size_t)bgi * Hi * Wi) * 128 + c;
  float acc = 0.f;
#pragma unroll
  for (int ky = 0; ky < 3; ++ky) {
    int ih = oh * 2 - 1 + ky;
    if ((unsigned)ih >= (unsigned)Hi) continue;
#pragma unroll
    for (int kx = 0; kx < 3; ++kx) {
      int iw = ow * 2 - 1 + kx;
      if ((unsigned)iw >= (unsigned)Wi) continue;
      acc += wgt[c * 9 + ky * 3 + kx] * cvt(ip[(size_t)(ih * Wi + iw) * IC]);
    }
  }
  if (fuse) {
    acc = (acc - bm_[c]) * rsqrtf(bv_[c] + 1e-5f) * bg_[c] + bb_[c];
    acc = gelu_f(acc);
  }
  stout(out + idx, acc);
}

// ---------------- fused K+V bilinear sample (dezeroed, NT stores) ----------
__global__ __launch_bounds__(256) void gatherkv_kernel(
    const unsigned short* __restrict__ Kimg, const unsigned short* __restrict__ Vimg,
    const int* __restrict__ goff, const float* __restrict__ gwt,
    unsigned short* __restrict__ Ks, unsigned short* __restrict__ Vs)
{
  int t = threadIdx.x;
  int pos = blockIdx.x * 8 + (t >> 5);   // 0..131071 = (b, nw, r)
  int oct = t & 31;                      // channel octet 0..31 (global 256 ch)
  int r = pos & 1023;
  int nw = (pos >> 10) & 63;
  int b = pos >> 16;
  int ch0 = oct * 8;
  int g = oct >> 4;                      // offset group for this channel half

  size_t cbase = ((size_t)(b * 2 + g) * 64 + nw) * 1024 + r;
  int base = goff[cbase];
  f32x4 wv = *(const f32x4*)(gwt + cbase * 4);
  int o00 = min(max(base, 0), 4095);
  int o01 = min(max(base + 1, 0), 4095);
  int o10 = min(max(base + 64, 0), 4095);
  int o11 = min(max(base + 65, 0), 4095);
  size_t pb = ((size_t)b * 4096) * 256 + ch0;
  uint4 kc[4], vc[4];
  kc[0] = *(const uint4*)(Kimg + pb + (size_t)o00 * 256);
  kc[1] = *(const uint4*)(Kimg + pb + (size_t)o01 * 256);
  kc[2] = *(const uint4*)(Kimg + pb + (size_t)o10 * 256);
  kc[3] = *(const uint4*)(Kimg + pb + (size_t)o11 * 256);
  vc[0] = *(const uint4*)(Vimg + pb + (size_t)o00 * 256);
  vc[1] = *(const uint4*)(Vimg + pb + (size_t)o01 * 256);
  vc[2] = *(const uint4*)(Vimg + pb + (size_t)o10 * 256);
  vc[3] = *(const uint4*)(Vimg + pb + (size_t)o11 * 256);

  float aK[8] = {0.f,0.f,0.f,0.f,0.f,0.f,0.f,0.f};
  float aV[8] = {0.f,0.f,0.f,0.f,0.f,0.f,0.f,0.f};
#pragma unroll
  for (int c4 = 0; c4 < 4; ++c4) {
    U16x8 ku, vu; ku.u4 = kc[c4]; vu.u4 = vc[c4];
    float wvv = wv[c4];
#pragma unroll
    for (int j = 0; j < 8; ++j) {
      aK[j] += wvv * b2f(ku.us[j]);
      aV[j] += wvv * b2f(vu.us[j]);
    }
  }
  U16x8 ok, ov;
#pragma unroll
  for (int j = 0; j < 8; ++j) { ok.us[j] = f2b(aK[j]); ov.us[j] = f2b(aV[j]); }
  int head = oct >> 2, chh = (oct & 3) * 8;
  size_t obase = (((size_t)(b * 8 + head) * 64 + nw) * 1024 + r) * 32 + chh;
  __builtin_nontemporal_store(ok.v4, (u32x4*)(Ks + obase));
  __builtin_nontemporal_store(ov.v4, (u32x4*)(Vs + obase));
}

// ---------------- attention on precomputed Ks/Vs ---------------------------
// r16 structure + exp2 fold + r21: paired-b32 PE bias reads (r17-proven
// mapping), s_setprio(1) around MFMA clusters.
__global__ __launch_bounds__(256) void attn2_kernel(
    const bf16* __restrict__ qbuf, const unsigned short* __restrict__ Ks,
    const unsigned short* __restrict__ Vs, const float* __restrict__ vbv,
    const float* __restrict__ pe, bf16* __restrict__ aout)
{
  __shared__ unsigned short vs[2][32][72];
  __shared__ unsigned short PsQs[64][72];
  __shared__ unsigned short pesb[70][72];

  const float LOG2E = 1.4426950408889634f;
  int blk = blockIdx.x;
  int b = blk & 1, head = (blk >> 1) & 7, nw = blk >> 4;
  int wh = nw >> 3, ww = nw & 7;
  int t = threadIdx.x;
  int lane = t & 63, w = t >> 6;
  int l15 = lane & 15, quad = lane >> 4;
  int qc0 = head * 32;
  int vr = t >> 2, vseg = t & 3;

  size_t kvbase = ((size_t)(b * 8 + head) * 64 + nw) * 32768;
  const unsigned short* Kb = Ks + kvbase;
  const unsigned short* Vb = Vs + kvbase;

  {
    int qt = t >> 2, oct = t & 3;
    int h = wh * 8 + (qt >> 3), wcol = ww * 8 + (qt & 7);
    const bf16* src = qbuf + ((size_t)b * 4096 + h * 64 + wcol) * 256 + qc0 + oct * 8;
    U16x8 u; u.u4 = *(const uint4*)src;
    U16x8 o;
#pragma unroll
    for (int j = 0; j < 8; ++j) o.us[j] = f2b(b2f(u.us[j]) * (0.0625f * LOG2E));
    *(uint4*)&PsQs[qt][oct * 8] = o.u4;
  }
  int ry0 = 56 - wh * 8, rx0 = 56 - ww * 8;
  for (int i = t; i < 70 * 70; i += 256) {
    int yy = i / 70, xx = i % 70;
    pesb[yy][xx] = f2b(pe[(size_t)head * 16129 + (ry0 + yy) * 127 + rx0 + xx] * LOG2E);
  }
  {
    U16x8 vu; vu.u4 = *(const uint4*)(Vb + (size_t)t * 8);
#pragma unroll
    for (int j = 0; j < 8; ++j) {
      int row = vseg * 8 + j;
      vs[0][row][vr ^ (((row >> 3) & 3) * 8)] = vu.us[j];
    }
  }
  uint4 kf[4];
#pragma unroll
  for (int nt = 0; nt < 4; ++nt)
    kf[nt] = *(const uint4*)(Kb + (size_t)(nt * 16 + l15) * 32 + quad * 8);
  __syncthreads();

  bf16x8 aQ = __builtin_bit_cast(bf16x8, *(const uint4*)&PsQs[w * 16 + l15][quad * 8]);
  float l[4] = {0.f, 0.f, 0.f, 0.f};
  f32x4 oacc[2];
  oacc[0] = (f32x4){0.f, 0.f, 0.f, 0.f};
  oacc[1] = (f32x4){0.f, 0.f, 0.f, 0.f};

  int rowbase = 7 - (w * 2 + (quad >> 1));      // + 4*c + 2*(nt>>1)
  int Cb = 2 * l15 + 7 - (quad & 1) * 4;        // + (nt&1)*32; cols C-3..C

  uint4 vcn = make_uint4(0u, 0u, 0u, 0u);
  uint4 kfn[4];
  for (int c = 0; c < 16; ++c) {
    int cur = c & 1;
    if (c) {
      // publish V tile c (loaded during stage c-1), then fence before PV reads
      U16x8 vu; vu.u4 = vcn;
#pragma unroll
      for (int j = 0; j < 8; ++j) {
        int row = vseg * 8 + j;
        vs[cur][row][vr ^ (((row >> 3) & 3) * 8)] = vu.us[j];
      }
      __syncthreads();
    }
    if (c < 15) {
      size_t nb = (size_t)(c * 64 + 64) * 32;
      vcn = *(const uint4*)(Vb + nb + (size_t)t * 8);
#pragma unroll
      for (int nt = 0; nt < 4; ++nt)
        kfn[nt] = *(const uint4*)(Kb + nb + (size_t)(nt * 16 + l15) * 32 + quad * 8);
    }

    f32x4 s[4];
    __builtin_amdgcn_s_setprio(1);
#pragma unroll
    for (int nt = 0; nt < 4; ++nt) {
      bf16x8 bK = __builtin_bit_cast(bf16x8, kf[nt]);
      f32x4 z = (f32x4){0.f, 0.f, 0.f, 0.f};
      s[nt] = __builtin_amdgcn_mfma_f32_16x16x32_bf16(aQ, bK, z, 0, 0, 0);
    }
    __builtin_amdgcn_s_setprio(0);
#pragma unroll
    for (int nt = 0; nt < 4; ++nt) {
      int row = rowbase + 4 * c + 2 * (nt >> 1);
      int C = Cb + (nt & 1) * 32;
      const unsigned int* pr = (const unsigned int*)&pesb[row][0];
      unsigned int pa = pr[(C - 3) >> 1];   // cols C-3 (lo), C-2 (hi)
      unsigned int pbm = pr[(C - 1) >> 1];  // cols C-1 (lo), C   (hi)
      s[nt][0] += hi2f(pbm);
      s[nt][1] += lo2f(pbm);
      s[nt][2] += hi2f(pa);
      s[nt][3] += lo2f(pa);
    }
#pragma unroll
    for (int reg = 0; reg < 4; ++reg) {
      float ps = 0.f;
#pragma unroll
      for (int nt = 0; nt < 4; ++nt) {
        float p = exp2f(s[nt][reg]);
        PsQs[w * 16 + quad * 4 + reg][nt * 16 + l15] = f2b(p);
        ps += p;
      }
      l[reg] += ps;   // cross-lane reduction deferred to after the loop
    }
    __builtin_amdgcn_s_setprio(1);
#pragma unroll
    for (int kst = 0; kst < 2; ++kst) {
      uint4 up = *(const uint4*)&PsQs[w * 16 + l15][kst * 32 + quad * 8];
      bf16x8 pA = __builtin_bit_cast(bf16x8, up);
#pragma unroll
      for (int nt2 = 0; nt2 < 2; ++nt2) {
        int row = nt2 * 16 + l15;
        int cbase = (kst * 32 + quad * 8) ^ (((row >> 3) & 3) * 8);
        uint4 uv = *(const uint4*)&vs[cur][row][cbase];
        bf16x8 vB = __builtin_bit_cast(bf16x8, uv);
        oacc[nt2] = __builtin_amdgcn_mfma_f32_16x16x32_bf16(pA, vB, oacc[nt2], 0, 0, 0);
      }
    }
    __builtin_amdgcn_s_setprio(0);
    if (c < 15) {
#pragma unroll
      for (int nt = 0; nt < 4; ++nt) kf[nt] = kfn[nt];
    }
  }
#pragma unroll
  for (int reg = 0; reg < 4; ++reg) {
    l[reg] += __shfl_xor(l[reg], 1, 64);
    l[reg] += __shfl_xor(l[reg], 2, 64);
    l[reg] += __shfl_xor(l[reg], 4, 64);
    l[reg] += __shfl_xor(l[reg], 8, 64);
  }
#pragma unroll
  for (int nt2 = 0; nt2 < 2; ++nt2) {
    float vbias = vbv[qc0 + nt2 * 16 + l15];
#pragma unroll
    for (int reg = 0; reg < 4; ++reg) {
      int q = w * 16 + quad * 4 + reg;
      size_t p = (size_t)b * 4096 + (wh * 8 + (q >> 3)) * 64 + ww * 8 + (q & 7);
      aout[p * 256 + qc0 + nt2 * 16 + l15] =
          __float2bfloat16(oacc[nt2][reg] / l[reg] + vbias);
    }
  }
}

// ---------------------------------------------------------------------------
extern "C" void kernel_launch(void* const* d_in, const int* in_sizes, int n_in,
                              void* d_out, int out_size, void* d_ws, size_t ws_size,
                              hipStream_t stream) {
  (void)in_sizes; (void)n_in; (void)out_size; (void)ws_size;
  const float* x     = (const float*)d_in[0];
  const float* ln1g  = (const float*)d_in[1];
  const float* ln1b  = (const float*)d_in[2];
  const float* q_w   = (const float*)d_in[3];
  const float* q_b   = (const float*)d_in[4];
  const float* k_w   = (const float*)d_in[5];
  const float* k_b   = (const float*)d_in[6];
  const float* v_w   = (const float*)d_in[7];
  const float* v_b   = (const float*)d_in[8];
  const float* off1w = (const float*)d_in[9];
  const float* off2w = (const float*)d_in[10];
  const float* off3w = (const float*)d_in[11];
  const float* bng   = (const float*)d_in[12];
  const float* bnb   = (const float*)d_in[13];
  const float* bnm   = (const float*)d_in[14];
  const float* bnv   = (const float*)d_in[15];
  const float* off4w = (const float*)d_in[16];
  const float* pe    = (const float*)d_in[17];
  const float* pjw   = (const float*)d_in[18];
  const float* pjb   = (const float*)d_in[19];
  const float* ln2g  = (const float*)d_in[20];
  const float* ln2b  = (const float*)d_in[21];
  const float* w1    = (const float*)d_in[22];
  const float* b1    = (const float*)d_in[23];
  const float* w2    = (const float*)d_in[24];
  const float* b2    = (const float*)d_in[25];
  (void)k_b;
  float* outp = (float*)d_out;

  char* W = (char*)d_ws;
  bf16*  xa    = (bf16*) (W + 0);          // [8192][256]; reused as aout/xm
  float* dw1   = (float*)(W + 8388608);    // [4][1024][128] f32
  float* dw2   = (float*)(W + 10485760);   // [4][256][128] f32
  bf16*  dw3b  = (bf16*) (W + 11010048);   // [4][64][128] bf16
  bf16*  qkv   = (bf16*) (W + 13238272);   // [3][8192][256] (q|K|V, dezeroed)
  bf16*  qb    = qkv;
  bf16*  Kimg  = qkv + 2097152;            // [2][4096][256]
  bf16*  Vimg  = qkv + 2 * 2097152;        // [2][4096][256]
  bf16*  x2    = (bf16*) (W + 34209792);
  float* xnhwc = (float*)(W + 38404096);
  unsigned short* wqkv   = (unsigned short*)(W + 46792704);
  float*          bqkv   = (float*)         (W + 47448064);
  unsigned short* wproj  = (unsigned short*)(W + 47453184);
  unsigned short* wmlp1  = (unsigned short*)(W + 47584256);
  unsigned short* wmlp2  = (unsigned short*)(W + 48108544);
  unsigned short* woff4i = (unsigned short*)(W + 48632832);
  int*   goff  = (int*)  (W + 49157120);
  float* gwt   = (float*)(W + 50205696);   // ends at 54,400,000
  unsigned short* Ksmp = (unsigned short*)(W + 54525952);   // 64 MiB
  unsigned short* Vsmp = (unsigned short*)(W + 121634816);  // 64 MiB
  bf16*  aout = xa;
  bf16*  xm   = xa;
  bf16*  hdn  = Kimg;                      // [8192][1024] bf16, after attn done

  // 1. setup: LN1 + all weight prep in one launch
  setup_kernel<<<4356, 256, 0, stream>>>(
      x, ln1g, ln1b, q_w, q_b, k_w, v_w, pjw, w1, w2, off4w,
      xa, xnhwc, wqkv, bqkv, wproj, wmlp1, wmlp2, woff4i);
  // 2. fused QKV GEMM: N=768 -> q | Kimg | Vimg (128x128 tile)
  mgemm_kernel<4, 0, 0, 128, 128><<<dim3(6, 64), 256, 0, stream>>>(
      xa, wqkv, bqkv, nullptr, qkv, 768, 256, 256, 256);
  // 3. offset branch: three parallel depthwise launches
  dwconv_kernel<bf16, float, 256><<<2048, 256, 0, stream>>>(
      qb, off1w, dw1, 64, 64, 32, 32, 0, nullptr, nullptr, nullptr, nullptr);
  dwconv_kernel<float, float, 128><<<512, 256, 0, stream>>>(
      dw1, off2w, dw2, 32, 32, 16, 16, 0, nullptr, nullptr, nullptr, nullptr);
  dwconv_kernel<float, bf16, 128><<<128, 256, 0, stream>>>(
      dw2, off3w, dw3b, 16, 16, 8, 8, 1, bng, bnb, bnm, bnv);
  // 4. offset head GEMM + tanh/grid + coord pack (OUTM=5, BM=64)
  mgemm_kernel<5, 0, 0, 64, 64><<<dim3(32, 4), 256, 0, stream>>>(
      dw3b, woff4i, nullptr, (const void*)gwt, goff, 2048, 128, 128, 128);
  // 5. attention: fused K+V sample (NT stores, no swizzle), then flash-attn
  gatherkv_kernel<<<16384, 256, 0, stream>>>(
      (const unsigned short*)Kimg, (const unsigned short*)Vimg,
      goff, gwt, Ksmp, Vsmp);
  attn2_kernel<<<1024, 256, 0, stream>>>(
      qb, Ksmp, Vsmp, v_b, pe, aout);
  // 6. proj + residual(x_nhwc f32) -> x2 NHWC bf16 (64x128 tile)
  mgemm_kernel<0, 1, 0, 64, 128><<<dim3(2, 128), 256, 0, stream>>>(
      aout, wproj, pjb, (const void*)xnhwc, x2, 256, 256, 256, 256);
  // 7. LN2 -> xm
  ln2_kernel<<<256, 256, 0, stream>>>(x2, ln2g, ln2b, xm);
  // 8. MLP1 + GELU -> hdn (128x128 tile)
  mgemm_kernel<0, 0, 1, 128, 128><<<dim3(8, 64), 256, 0, stream>>>(
      xm, wmlp1, b1, nullptr, hdn, 1024, 256, 256, 256);
  // 9. MLP2 + residual(x2) -> f32 NCHW d_out via LDS transpose (BN=64)
  mgemm_kernel<1, 2, 0, 64, 64><<<dim3(4, 128), 256, 0, stream>>>(
      hdn, wmlp2, b2, (const void*)x2, outp, 256, 1024, 1024, 1024);
}

// Round 10
// 276.968 us; speedup vs baseline: 1.0070x; 1.0070x over previous
//
#include <hip/hip_runtime.h>
#include <hip/hip_bf16.h>
#include <math.h>

// CBiAFormerBlock fused implementation, round 22.
// Post-mortem r21 (278.9us, neutral): GEMM tile widening + attn micro-fixes
// all within noise; attn2 intra-kernel schedule exhausted.  Launch shapes
// reverted to r20-exact.
// r22: FUSE gather back into attention (attn4).  r12's proven structure
// (112us) minus every confound since removed:
//  - dezeroed images: single offset-group per head (head*32 ch in one group)
//    -> 4 corner loads/img (was 8), 64 interp FMA/thread/stage (was 256).
//  - deferred softmax cross-lane reduction (r14), exp2-fold (r17),
//    b32-paired PE reads (r21), setprio around MFMA clusters.
// Removes gatherkv (~38us) + the 128MB Ks/Vs HBM round trip entirely;
// corner reads hit L2 (block's K+V images = 4MB).  All non-attn kernels
// r20-exact.

typedef __hip_bfloat16 bf16;
typedef __bf16 bf16x8 __attribute__((ext_vector_type(8)));
typedef float f32x4 __attribute__((ext_vector_type(4)));
typedef unsigned int u32x4 __attribute__((ext_vector_type(4)));

union U16x8 { uint4 u4; u32x4 v4; unsigned short us[8]; };
union FU { float f; unsigned int u; };

__device__ __forceinline__ float cvt(float x) { return x; }
__device__ __forceinline__ float cvt(bf16 x) { return __bfloat162float(x); }
__device__ __forceinline__ float b2f(unsigned short u) {
  union { float f; unsigned int v; } x; x.v = ((unsigned int)u) << 16; return x.f;
}
__device__ __forceinline__ float hi2f(unsigned int u) {
  FU x; x.u = u & 0xffff0000u; return x.f;
}
__device__ __forceinline__ float lo2f(unsigned int u) {
  FU x; x.u = u << 16; return x.f;
}
__device__ __forceinline__ unsigned short f2b(float f) {
  bf16 h = __float2bfloat16(f);
  return *reinterpret_cast<unsigned short*>(&h);
}
__device__ __forceinline__ float gelu_f(float x) {
  return 0.5f * x * (1.0f + erff(x * 0.7071067811865475f));
}
__device__ __forceinline__ void stout(float* p, float v) { *p = v; }
__device__ __forceinline__ void stout(bf16* p, float v) { *p = __float2bfloat16(v); }

// ---------------- setup: LN1 (blocks 0..255) UNION weight prep (256..4355) --
__global__ __launch_bounds__(256) void setup_kernel(
    const float* __restrict__ x, const float* __restrict__ g,
    const float* __restrict__ bta,
    const float* __restrict__ q_w, const float* __restrict__ q_b,
    const float* __restrict__ k_w, const float* __restrict__ v_w,
    const float* __restrict__ pjw, const float* __restrict__ w1,
    const float* __restrict__ w2, const float* __restrict__ off4w,
    bf16* __restrict__ out, float* __restrict__ xnhwc,
    unsigned short* __restrict__ wqkv, float* __restrict__ bqkv,
    unsigned short* __restrict__ wproj, unsigned short* __restrict__ wmlp1,
    unsigned short* __restrict__ wmlp2, unsigned short* __restrict__ woff4i)
{
  __shared__ float s1[8][32], s2[8][32];
  __shared__ unsigned short tb[32][264];
  int bid = blockIdx.x;
  int t = threadIdx.x;
  if (bid < 256) {
    int pos = t & 31, cs = t >> 5;
    int p = bid * 32 + pos;
    int bb = p >> 12, hw = p & 4095;
    const float* xp = x + (size_t)bb * 256 * 4096 + hw;
    float vloc[32];
    float sum = 0.f, ss = 0.f;
#pragma unroll
    for (int i = 0; i < 32; ++i) {
      float v = xp[(size_t)(cs * 32 + i) * 4096];
      vloc[i] = v; sum += v; ss += v * v;
    }
    s1[cs][pos] = sum; s2[cs][pos] = ss;
    {
      float* xo = xnhwc + (size_t)p * 256 + cs * 32;
#pragma unroll
      for (int qd = 0; qd < 8; ++qd)
        *(float4*)(xo + qd * 4) = make_float4(vloc[qd*4], vloc[qd*4+1],
                                              vloc[qd*4+2], vloc[qd*4+3]);
    }
    __syncthreads();
    if (cs == 0) {
      float S = 0.f, Q = 0.f;
#pragma unroll
      for (int i = 0; i < 8; ++i) { S += s1[i][pos]; Q += s2[i][pos]; }
      float mu = S * (1.f / 256.f);
      float var = Q * (1.f / 256.f) - mu * mu;
      s1[0][pos] = mu;
      s2[0][pos] = rsqrtf(var + 1e-5f);
    }
    __syncthreads();
    float mu = s1[0][pos], rs = s2[0][pos];
#pragma unroll
    for (int i = 0; i < 32; ++i) {
      int c = cs * 32 + i;
      tb[pos][c] = f2b((vloc[i] - mu) * rs * g[c] + bta[c]);
    }
    __syncthreads();
    int px = t >> 3, grp = t & 7;
    bf16* op = out + ((size_t)bid * 32 + px) * 256 + grp * 32;
#pragma unroll
    for (int q = 0; q < 4; ++q)
      *(uint4*)(op + q * 8) = *(const uint4*)&tb[px][grp * 32 + q * 8];
  } else {
    int idx = (bid - 256) * 256 + t;
    const int S0 = 768 * 256;          // q|K|V weights, dezeroed
    const int S1 = S0 + 768;           // bias
    const int S2 = S1 + 256 * 256;
    const int S3 = S2 + 1024 * 256;
    const int S4 = S3 + 256 * 1024;
    const int S5 = S4 + 2048 * 128;
    if (idx < S0) {
      int n = idx >> 8, c = idx & 255;
      float v;
      if (n < 256)       v = q_w[n * 256 + c];
      else if (n < 512)  v = k_w[(n - 256) * 256 + c];
      else               v = v_w[(n - 512) * 256 + c];
      wqkv[idx] = f2b(v);
    } else if (idx < S1) {
      int n = idx - S0;
      bqkv[n] = (n < 256) ? q_b[n] : 0.f;
    } else if (idx < S2) {
      wproj[idx - S1] = f2b(pjw[idx - S1]);
    } else if (idx < S3) {
      wmlp1[idx - S2] = f2b(w1[idx - S2]);
    } else if (idx < S4) {
      wmlp2[idx - S3] = f2b(w2[idx - S3]);
    } else if (idx < S5) {
      int kk = idx - S4;
      int n = kk >> 7, c = kk & 127;
      // interleaved: n = 2r + coord  <-  off4w row coord*1024 + r
      woff4i[kk] = f2b(off4w[((size_t)((n & 1) * 1024 + (n >> 1))) * 128 + c]);
    }
  }
}

// ---------------- LN2: NHWC bf16 in -> NHWC bf16 out -----------------------
__global__ __launch_bounds__(256) void ln2_kernel(
    const bf16* __restrict__ xin, const float* __restrict__ g,
    const float* __restrict__ bta, bf16* __restrict__ out)
{
  __shared__ float sa[8][32], sb[8][32];
  __shared__ float mu_s[32], rs_s[32];
  int t = threadIdx.x;
  int px = t >> 3, grp = t & 7;
  size_t p = (size_t)blockIdx.x * 32 + px;
  const bf16* xp = xin + p * 256 + grp * 32;
  float v[32]; float sum = 0.f, ss = 0.f;
#pragma unroll
  for (int q = 0; q < 4; ++q) {
    U16x8 u; u.u4 = *(const uint4*)(xp + q * 8);
#pragma unroll
    for (int j = 0; j < 8; ++j) {
      float f = b2f(u.us[j]); v[q * 8 + j] = f; sum += f; ss += f * f;
    }
  }
  sa[grp][px] = sum; sb[grp][px] = ss;
  __syncthreads();
  if (t < 32) {
    float S = 0.f, Q = 0.f;
#pragma unroll
    for (int i = 0; i < 8; ++i) { S += sa[i][t]; Q += sb[i][t]; }
    float mu = S * (1.f / 256.f);
    mu_s[t] = mu;
    rs_s[t] = rsqrtf(Q * (1.f / 256.f) - mu * mu + 1e-5f);
  }
  __syncthreads();
  float mu = mu_s[px], rs = rs_s[px];
  bf16* op = out + p * 256 + grp * 32;
#pragma unroll
  for (int q = 0; q < 4; ++q) {
    U16x8 o;
#pragma unroll
    for (int j = 0; j < 8; ++j) {
      int c = grp * 32 + q * 8 + j;
      o.us[j] = f2b((v[q * 8 + j] - mu) * rs * g[c] + bta[c]);
    }
    *(uint4*)(op + q * 8) = o.u4;
  }
}

// ---------------- MFMA GEMM (NHWC): out[p][o] = sum_c A[p][c] W[o][c] ------
// OUTM: 0 bf16 NHWC; 1 f32 NCHW via LDS transpose (BN=64 only); 4 grouped-
//       QKV; 5 offset-grid head + coord pack (out=goff, res=gwt).
// RESM: 0 none; 1 f32 NHWC; 2 bf16 NHWC. ACT: 1 exact GELU.
template<int OUTM, int RESM, int ACT, int BM, int BN>
__global__ __launch_bounds__(256) void mgemm_kernel(
    const bf16* __restrict__ A, const unsigned short* __restrict__ Bw,
    const float* __restrict__ bias, const void* __restrict__ res,
    void* __restrict__ out, int N, int K, int lda, int ldb)
{
  constexpr int MT = BM / 32;
  constexpr int WNT = BN / 32;
  constexpr int AB_BYTES = (BM + BN) * 72 * 2;
  constexpr int T_LD = BM + 5;
  constexpr int T_BYTES = 64 * T_LD * 4;
  constexpr int SH_BYTES = (OUTM == 1 && T_BYTES > AB_BYTES) ? T_BYTES : AB_BYTES;
  __shared__ __attribute__((aligned(16))) char shraw[SH_BYTES];
  auto As = reinterpret_cast<unsigned short(*)[72]>(shraw);
  auto Bs = reinterpret_cast<unsigned short(*)[72]>(shraw + BM * 72 * 2);
  float (*T)[T_LD] = reinterpret_cast<float(*)[T_LD]>(shraw);

  int t = threadIdx.x;
  int m0 = blockIdx.y * BM, n0 = blockIdx.x * BN;
  int lane = t & 63, w = t >> 6;
  int l15 = lane & 15, quad = lane >> 4;
  int wm = (w >> 1) * (BM / 2), wn = (w & 1) * (BN / 2);
  f32x4 acc[MT][WNT];
#pragma unroll
  for (int mt = 0; mt < MT; ++mt)
#pragma unroll
    for (int nt = 0; nt < WNT; ++nt) acc[mt][nt] = (f32x4){0.f, 0.f, 0.f, 0.f};

  for (int k0 = 0; k0 < K; k0 += 64) {
#pragma unroll
    for (int i = 0; i < MT; ++i) {
      int idx = t + i * 256;
      int m = idx >> 3, oc = (idx & 7) * 8;
      *(uint4*)&As[m][oc] = *(const uint4*)(A + (size_t)(m0 + m) * lda + k0 + oc);
    }
#pragma unroll
    for (int i = 0; i < WNT; ++i) {
      int idx = t + i * 256;
      int n = idx >> 3, oc = (idx & 7) * 8;
      *(uint4*)&Bs[n][oc] = *(const uint4*)(Bw + (size_t)(n0 + n) * ldb + k0 + oc);
    }
    __syncthreads();
#pragma unroll
    for (int ks = 0; ks < 2; ++ks) {
      bf16x8 af[MT], bfr[WNT];
#pragma unroll
      for (int mt = 0; mt < MT; ++mt)
        af[mt] = __builtin_bit_cast(bf16x8,
            *(const uint4*)&As[wm + mt * 16 + l15][ks * 32 + quad * 8]);
#pragma unroll
      for (int nt = 0; nt < WNT; ++nt)
        bfr[nt] = __builtin_bit_cast(bf16x8,
            *(const uint4*)&Bs[wn + nt * 16 + l15][ks * 32 + quad * 8]);
#pragma unroll
      for (int mt = 0; mt < MT; ++mt)
#pragma unroll
        for (int nt = 0; nt < WNT; ++nt)
          acc[mt][nt] = __builtin_amdgcn_mfma_f32_16x16x32_bf16(
              af[mt], bfr[nt], acc[mt][nt], 0, 0, 0);
    }
    __syncthreads();
  }
  float bv[WNT];
#pragma unroll
  for (int nt = 0; nt < WNT; ++nt)
    bv[nt] = bias ? bias[n0 + wn + nt * 16 + l15] : 0.f;
#pragma unroll
  for (int mt = 0; mt < MT; ++mt) {
#pragma unroll
    for (int nt = 0; nt < WNT; ++nt) {
#pragma unroll
      for (int reg = 0; reg < 4; ++reg) {
        int m = m0 + wm + mt * 16 + quad * 4 + reg;
        int n = n0 + wn + nt * 16 + l15;
        float v = acc[mt][nt][reg] + bv[nt];
        if constexpr (ACT == 1) v = gelu_f(v);
        if constexpr (RESM == 1)
          v += ((const float*)res)[(size_t)m * N + n];
        if constexpr (RESM == 2)
          v += b2f(((const unsigned short*)res)[(size_t)m * N + n]);
        if constexpr (OUTM == 0)
          ((unsigned short*)out)[(size_t)m * N + n] = f2b(v);
        if constexpr (OUTM == 1)
          T[(n - n0)][(m - m0)] = v;
        if constexpr (OUTM == 4)
          ((unsigned short*)out)[((size_t)(n >> 8) * 8192 + m) * 256 + (n & 255)] = f2b(v);
        if constexpr (OUTM == 5) {
          float val = tanhf(v) * (2.0f / 64.0f);
          int r = n >> 1, coord = n & 1;
          int rc = coord ? (r & 31) : (r >> 5);
          float ref = rc * (4.0f / 63.0f) - 1.0f;
          float pix = (val + ref + 1.0f) * 31.5f;
          float other = __shfl_xor(pix, 1, 64);
          if (coord == 0) {
            float rowp = pix, colp = other;
            float r0f = floorf(rowp), c0f = floorf(colp);
            float wr = rowp - r0f, wc = colp - c0f;
            int r0 = (int)r0f, c0 = (int)c0f;
            bool rv0 = ((unsigned)r0 < 64u), rv1 = ((unsigned)(r0 + 1) < 64u);
            bool cv0 = ((unsigned)c0 < 64u), cv1 = ((unsigned)(c0 + 1) < 64u);
            float4 w4;
            w4.x = (rv0 && cv0) ? (1.f - wr) * (1.f - wc) : 0.f;
            w4.y = (rv0 && cv1) ? (1.f - wr) * wc : 0.f;
            w4.z = (rv1 && cv0) ? wr * (1.f - wc) : 0.f;
            w4.w = (rv1 && cv1) ? wr * wc : 0.f;
            ((int*)out)[(size_t)m * 1024 + r] = r0 * 64 + c0;
            *(float4*)((float*)res + ((size_t)m * 1024 + r) * 4) = w4;
          }
        }
      }
    }
  }
  if constexpr (OUTM == 1) {
    __syncthreads();
    constexpr int SEGS = BM / 32;
    int units = 64 * SEGS;
    if (t < units) {
      int nl = t / SEGS, seg = t % SEGS;
      int bI = m0 >> 12, hw0 = m0 & 4095;
      float* op = (float*)out + ((size_t)bI * 256 + n0 + nl) * 4096 + hw0 + seg * 32;
#pragma unroll
      for (int k = 0; k < 32; ++k) op[k] = T[nl][seg * 32 + k];
    }
  }
}

// ---------------- depthwise 3x3 stride-2 pad-1 conv, NHWC-128 --------------
template<typename TI, typename TO, int IC>
__global__ __launch_bounds__(256) void dwconv_kernel(
    const TI* __restrict__ in, const float* __restrict__ wgt,
    TO* __restrict__ out, int Hi, int Wi, int Ho, int Wo, int fuse,
    const float* __restrict__ bg_, const float* __restrict__ bb_,
    const float* __restrict__ bm_, const float* __restrict__ bv_)
{
  int idx = blockIdx.x * 256 + threadIdx.x;
  int c = idx & 127;
  int pp = idx >> 7;
  int ow = pp % Wo, oh = (pp / Wo) % Ho, bgi = pp / (Wo * Ho);
  const TI* ip;
  if constexpr (IC == 256)
    ip = in + ((size_t)(bgi >> 1) * 4096) * 256 + (bgi & 1) * 128 + c;
  else
    ip = in + ((size_t)bgi * Hi * Wi) * 128 + c;
  float acc = 0.f;
#pragma unroll
  for (int ky = 0; ky < 3; ++ky) {
    int ih = oh * 2 - 1 + ky;
    if ((unsigned)ih >= (unsigned)Hi) continue;
#pragma unroll
    for (int kx = 0; kx < 3; ++kx) {
      int iw = ow * 2 - 1 + kx;
      if ((unsigned)iw >= (unsigned)Wi) continue;
      acc += wgt[c * 9 + ky * 3 + kx] * cvt(ip[(size_t)(ih * Wi + iw) * IC]);
    }
  }
  if (fuse) {
    acc = (acc - bm_[c]) * rsqrtf(bv_[c] + 1e-5f) * bg_[c] + bb_[c];
    acc = gelu_f(acc);
  }
  stout(out + idx, acc);
}

// ---------------- r22: fused deformable attention (in-kernel gather) -------
// r12's proven structure modernized: dezeroed images (single offset-group
// per head -> 4 corner loads/img, 64 interp FMA/thread/stage), K tile +
// XOR-swizzled V tile double-buffered in LDS, 1 barrier/stage, deferred
// softmax reduction, exp2-fold, b32-paired PE reads, setprio MFMA clusters.
__global__ __launch_bounds__(256) void attn4_kernel(
    const bf16* __restrict__ qbuf, const unsigned short* __restrict__ Kimg,
    const unsigned short* __restrict__ Vimg, const int* __restrict__ goff,
    const float* __restrict__ gwt, const float* __restrict__ vbv,
    const float* __restrict__ pe, bf16* __restrict__ aout)
{
  __shared__ unsigned short ks[2][64][40];
  __shared__ unsigned short vs[2][32][72];
  __shared__ unsigned short PsQs[64][72];
  __shared__ unsigned short pesb[70][72];

  const float LOG2E = 1.4426950408889634f;
  int blk = blockIdx.x;
  int b = blk & 1, head = (blk >> 1) & 7, nw = blk >> 4;
  int wh = nw >> 3, ww = nw & 7;
  int t = threadIdx.x;
  int lane = t & 63, w = t >> 6;
  int l15 = lane & 15, quad = lane >> 4;
  int qc0 = head * 32;
  int g = head >> 2;                       // this head's offset group
  int gr_r = t >> 2, gr_seg = t & 3;
  int choff = qc0 + gr_seg * 8;
  size_t cb0 = ((size_t)(b * 2 + g) * 64 + nw) * 1024 + gr_r;
  size_t pbK = (size_t)b * 4096 * 256 + choff;

  uint4 kc[4], vc[4];
  f32x4 wv;
  auto gather = [&](int rc0) {
    size_t cbase = cb0 + rc0;
    int base = goff[cbase];
    wv = *(const f32x4*)(gwt + cbase * 4);
    int o00 = min(max(base, 0), 4095);
    int o01 = min(max(base + 1, 0), 4095);
    int o10 = min(max(base + 64, 0), 4095);
    int o11 = min(max(base + 65, 0), 4095);
    kc[0] = *(const uint4*)(Kimg + pbK + (size_t)o00 * 256);
    kc[1] = *(const uint4*)(Kimg + pbK + (size_t)o01 * 256);
    kc[2] = *(const uint4*)(Kimg + pbK + (size_t)o10 * 256);
    kc[3] = *(const uint4*)(Kimg + pbK + (size_t)o11 * 256);
    vc[0] = *(const uint4*)(Vimg + pbK + (size_t)o00 * 256);
    vc[1] = *(const uint4*)(Vimg + pbK + (size_t)o01 * 256);
    vc[2] = *(const uint4*)(Vimg + pbK + (size_t)o10 * 256);
    vc[3] = *(const uint4*)(Vimg + pbK + (size_t)o11 * 256);
  };
  auto combine = [&](int buf) {
    float aK[8] = {0.f,0.f,0.f,0.f,0.f,0.f,0.f,0.f};
    float aV[8] = {0.f,0.f,0.f,0.f,0.f,0.f,0.f,0.f};
#pragma unroll
    for (int c4 = 0; c4 < 4; ++c4) {
      U16x8 ku, vu; ku.u4 = kc[c4]; vu.u4 = vc[c4];
      float wvv = wv[c4];
#pragma unroll
      for (int j = 0; j < 8; ++j) {
        aK[j] += wvv * b2f(ku.us[j]);
        aV[j] += wvv * b2f(vu.us[j]);
      }
    }
    U16x8 ok;
#pragma unroll
    for (int j = 0; j < 8; ++j) ok.us[j] = f2b(aK[j]);
    *(uint4*)&ks[buf][gr_r][gr_seg * 8] = ok.u4;
#pragma unroll
    for (int j = 0; j < 8; ++j) {
      int row = gr_seg * 8 + j;
      vs[buf][row][gr_r ^ (((row >> 3) & 3) * 8)] = f2b(aV[j]);
    }
  };

  {
    int qt = t >> 2, oct = t & 3;
    int h = wh * 8 + (qt >> 3), wcol = ww * 8 + (qt & 7);
    const bf16* src = qbuf + ((size_t)b * 4096 + h * 64 + wcol) * 256 + qc0 + oct * 8;
    U16x8 u; u.u4 = *(const uint4*)src;
    U16x8 o;
#pragma unroll
    for (int j = 0; j < 8; ++j) o.us[j] = f2b(b2f(u.us[j]) * (0.0625f * LOG2E));
    *(uint4*)&PsQs[qt][oct * 8] = o.u4;
  }
  int ry0 = 56 - wh * 8, rx0 = 56 - ww * 8;
  for (int i = t; i < 70 * 70; i += 256) {
    int yy = i / 70, xx = i % 70;
    pesb[yy][xx] = f2b(pe[(size_t)head * 16129 + (ry0 + yy) * 127 + rx0 + xx] * LOG2E);
  }
  gather(0);
  combine(0);
  __syncthreads();

  bf16x8 aQ = __builtin_bit_cast(bf16x8, *(const uint4*)&PsQs[w * 16 + l15][quad * 8]);
  float l[4] = {0.f, 0.f, 0.f, 0.f};
  f32x4 oacc[2];
  oacc[0] = (f32x4){0.f, 0.f, 0.f, 0.f};
  oacc[1] = (f32x4){0.f, 0.f, 0.f, 0.f};

  int rowbase = 7 - (w * 2 + (quad >> 1));      // + 4*c + 2*(nt>>1)
  int Cb = 2 * l15 + 7 - (quad & 1) * 4;        // + (nt&1)*32; cols C-3..C

  for (int c = 0; c < 16; ++c) {
    int cur = c & 1;
    if (c) __syncthreads();
    if (c < 15) gather(c * 64 + 64);   // issue next tile's corner loads early

    f32x4 s[4];
    __builtin_amdgcn_s_setprio(1);
#pragma unroll
    for (int nt = 0; nt < 4; ++nt) {
      uint4 u = *(const uint4*)&ks[cur][nt * 16 + l15][quad * 8];
      bf16x8 bK = __builtin_bit_cast(bf16x8, u);
      f32x4 z = (f32x4){0.f, 0.f, 0.f, 0.f};
      s[nt] = __builtin_amdgcn_mfma_f32_16x16x32_bf16(aQ, bK, z, 0, 0, 0);
    }
    __builtin_amdgcn_s_setprio(0);
#pragma unroll
    for (int nt = 0; nt < 4; ++nt) {
      int row = rowbase + 4 * c + 2 * (nt >> 1);
      int C = Cb + (nt & 1) * 32;
      const unsigned int* pr = (const unsigned int*)&pesb[row][0];
      unsigned int pa = pr[(C - 3) >> 1];   // cols C-3 (lo), C-2 (hi)
      unsigned int pbm = pr[(C - 1) >> 1];  // cols C-1 (lo), C   (hi)
      s[nt][0] += hi2f(pbm);
      s[nt][1] += lo2f(pbm);
      s[nt][2] += hi2f(pa);
      s[nt][3] += lo2f(pa);
    }
#pragma unroll
    for (int reg = 0; reg < 4; ++reg) {
      float ps = 0.f;
#pragma unroll
      for (int nt = 0; nt < 4; ++nt) {
        float p = exp2f(s[nt][reg]);
        PsQs[w * 16 + quad * 4 + reg][nt * 16 + l15] = f2b(p);
        ps += p;
      }
      l[reg] += ps;   // cross-lane reduction deferred to after the loop
    }
    __builtin_amdgcn_s_setprio(1);
#pragma unroll
    for (int kst = 0; kst < 2; ++kst) {
      uint4 up = *(const uint4*)&PsQs[w * 16 + l15][kst * 32 + quad * 8];
      bf16x8 pA = __builtin_bit_cast(bf16x8, up);
#pragma unroll
      for (int nt2 = 0; nt2 < 2; ++nt2) {
        int row = nt2 * 16 + l15;
        int cbase = (kst * 32 + quad * 8) ^ (((row >> 3) & 3) * 8);
        uint4 uv = *(const uint4*)&vs[cur][row][cbase];
        bf16x8 vB = __builtin_bit_cast(bf16x8, uv);
        oacc[nt2] = __builtin_amdgcn_mfma_f32_16x16x32_bf16(pA, vB, oacc[nt2], 0, 0, 0);
      }
    }
    __builtin_amdgcn_s_setprio(0);
    if (c < 15) combine(cur ^ 1);
  }
#pragma unroll
  for (int reg = 0; reg < 4; ++reg) {
    l[reg] += __shfl_xor(l[reg], 1, 64);
    l[reg] += __shfl_xor(l[reg], 2, 64);
    l[reg] += __shfl_xor(l[reg], 4, 64);
    l[reg] += __shfl_xor(l[reg], 8, 64);
  }
#pragma unroll
  for (int nt2 = 0; nt2 < 2; ++nt2) {
    float vbias = vbv[qc0 + nt2 * 16 + l15];
#pragma unroll
    for (int reg = 0; reg < 4; ++reg) {
      int q = w * 16 + quad * 4 + reg;
      size_t p = (size_t)b * 4096 + (wh * 8 + (q >> 3)) * 64 + ww * 8 + (q & 7);
      aout[p * 256 + qc0 + nt2 * 16 + l15] =
          __float2bfloat16(oacc[nt2][reg] / l[reg] + vbias);
    }
  }
}

// ---------------------------------------------------------------------------
extern "C" void kernel_launch(void* const* d_in, const int* in_sizes, int n_in,
                              void* d_out, int out_size, void* d_ws, size_t ws_size,
                              hipStream_t stream) {
  (void)in_sizes; (void)n_in; (void)out_size; (void)ws_size;
  const float* x     = (const float*)d_in[0];
  const float* ln1g  = (const float*)d_in[1];
  const float* ln1b  = (const float*)d_in[2];
  const float* q_w   = (const float*)d_in[3];
  const float* q_b   = (const float*)d_in[4];
  const float* k_w   = (const float*)d_in[5];
  const float* k_b   = (const float*)d_in[6];
  const float* v_w   = (const float*)d_in[7];
  const float* v_b   = (const float*)d_in[8];
  const float* off1w = (const float*)d_in[9];
  const float* off2w = (const float*)d_in[10];
  const float* off3w = (const float*)d_in[11];
  const float* bng   = (const float*)d_in[12];
  const float* bnb   = (const float*)d_in[13];
  const float* bnm   = (const float*)d_in[14];
  const float* bnv   = (const float*)d_in[15];
  const float* off4w = (const float*)d_in[16];
  const float* pe    = (const float*)d_in[17];
  const float* pjw   = (const float*)d_in[18];
  const float* pjb   = (const float*)d_in[19];
  const float* ln2g  = (const float*)d_in[20];
  const float* ln2b  = (const float*)d_in[21];
  const float* w1    = (const float*)d_in[22];
  const float* b1    = (const float*)d_in[23];
  const float* w2    = (const float*)d_in[24];
  const float* b2    = (const float*)d_in[25];
  (void)k_b;
  float* outp = (float*)d_out;

  char* W = (char*)d_ws;
  bf16*  xa    = (bf16*) (W + 0);          // [8192][256]; reused as aout/xm
  float* dw1   = (float*)(W + 8388608);    // [4][1024][128] f32
  float* dw2   = (float*)(W + 10485760);   // [4][256][128] f32
  bf16*  dw3b  = (bf16*) (W + 11010048);   // [4][64][128] bf16
  bf16*  qkv   = (bf16*) (W + 13238272);   // [3][8192][256] (q|K|V, dezeroed)
  bf16*  qb    = qkv;
  bf16*  Kimg  = qkv + 2097152;            // [2][4096][256]
  bf16*  Vimg  = qkv + 2 * 2097152;        // [2][4096][256]
  bf16*  x2    = (bf16*) (W + 34209792);
  float* xnhwc = (float*)(W + 38404096);
  unsigned short* wqkv   = (unsigned short*)(W + 46792704);
  float*          bqkv   = (float*)         (W + 47448064);
  unsigned short* wproj  = (unsigned short*)(W + 47453184);
  unsigned short* wmlp1  = (unsigned short*)(W + 47584256);
  unsigned short* wmlp2  = (unsigned short*)(W + 48108544);
  unsigned short* woff4i = (unsigned short*)(W + 48632832);
  int*   goff  = (int*)  (W + 49157120);
  float* gwt   = (float*)(W + 50205696);   // ends at 54,400,000
  bf16*  aout = xa;
  bf16*  xm   = xa;
  bf16*  hdn  = Kimg;                      // [8192][1024] bf16, after attn done

  // 1. setup: LN1 + all weight prep in one launch
  setup_kernel<<<4356, 256, 0, stream>>>(
      x, ln1g, ln1b, q_w, q_b, k_w, v_w, pjw, w1, w2, off4w,
      xa, xnhwc, wqkv, bqkv, wproj, wmlp1, wmlp2, woff4i);
  // 2. fused QKV GEMM: N=768 -> q | Kimg | Vimg (dezeroed)
  mgemm_kernel<4, 0, 0, 128, 64><<<dim3(12, 64), 256, 0, stream>>>(
      xa, wqkv, bqkv, nullptr, qkv, 768, 256, 256, 256);
  // 3. offset branch: three parallel depthwise launches
  dwconv_kernel<bf16, float, 256><<<2048, 256, 0, stream>>>(
      qb, off1w, dw1, 64, 64, 32, 32, 0, nullptr, nullptr, nullptr, nullptr);
  dwconv_kernel<float, float, 128><<<512, 256, 0, stream>>>(
      dw1, off2w, dw2, 32, 32, 16, 16, 0, nullptr, nullptr, nullptr, nullptr);
  dwconv_kernel<float, bf16, 128><<<128, 256, 0, stream>>>(
      dw2, off3w, dw3b, 16, 16, 8, 8, 1, bng, bnb, bnm, bnv);
  // 4. offset head GEMM + tanh/grid + coord pack (OUTM=5, BM=64)
  mgemm_kernel<5, 0, 0, 64, 64><<<dim3(32, 4), 256, 0, stream>>>(
      dw3b, woff4i, nullptr, (const void*)gwt, goff, 2048, 128, 128, 128);
  // 5. fused deformable attention (in-kernel gather, no Ks/Vs round trip)
  attn4_kernel<<<1024, 256, 0, stream>>>(
      qb, (const unsigned short*)Kimg, (const unsigned short*)Vimg,
      goff, gwt, v_b, pe, aout);
  // 6. proj + residual(x_nhwc f32) -> x2 NHWC bf16
  mgemm_kernel<0, 1, 0, 64, 64><<<dim3(4, 128), 256, 0, stream>>>(
      aout, wproj, pjb, (const void*)xnhwc, x2, 256, 256, 256, 256);
  // 7. LN2 -> xm
  ln2_kernel<<<256, 256, 0, stream>>>(x2, ln2g, ln2b, xm);
  // 8. MLP1 + GELU -> hdn
  mgemm_kernel<0, 0, 1, 128, 64><<<dim3(16, 64), 256, 0, stream>>>(
      xm, wmlp1, b1, nullptr, hdn, 1024, 256, 256, 256);
  // 9. MLP2 + residual(x2) -> f32 NCHW d_out via LDS transpose
  mgemm_kernel<1, 2, 0, 64, 64><<<dim3(4, 128), 256, 0, stream>>>(
      hdn, wmlp2, b2, (const void*)x2, outp, 256, 1024, 1024, 1024);
}

// Round 11
// 257.673 us; speedup vs baseline: 1.0824x; 1.0749x over previous
//
#include <hip/hip_runtime.h>
#include <hip/hip_bf16.h>
#include <math.h>

// CBiAFormerBlock fused implementation, round 23.
// Post-mortem r22 (276.97us ~ tie w/ r20's 276.34): attn4 fusion killed the
// 128MB round trip (FETCH 70->26MB) but attn4=78.6us.  Counter arithmetic:
// VALU-issue = ~40us of it (VALUBusy 52%; ~165 VALU/thread/stage interp
// unpack+FMA+pack matches 96K cycles/CU).  Bank conflicts 3.19M (ks stride
// 40: rows alias 8 banks x2).
// r23: cut the measured VALU term, keep structure.
//  - interp combine as float2 ops -> v_pk_fma_f32 (64->32 FMA instrs/stage);
//    per-element accumulation order unchanged (bit-identical).
//  - ks stride 40->36: row banks = row*18%32, all 16 distinct; 2-way worst
//    case (free).  -1KB LDS.
// All else byte-identical to r22.

typedef __hip_bfloat16 bf16;
typedef __bf16 bf16x8 __attribute__((ext_vector_type(8)));
typedef float f32x4 __attribute__((ext_vector_type(4)));
typedef float f32x2 __attribute__((ext_vector_type(2)));
typedef unsigned int u32x4 __attribute__((ext_vector_type(4)));

union U16x8 { uint4 u4; u32x4 v4; unsigned int uw[4]; unsigned short us[8]; };
union FU { float f; unsigned int u; };

__device__ __forceinline__ float cvt(float x) { return x; }
__device__ __forceinline__ float cvt(bf16 x) { return __bfloat162float(x); }
__device__ __forceinline__ float b2f(unsigned short u) {
  union { float f; unsigned int v; } x; x.v = ((unsigned int)u) << 16; return x.f;
}
__device__ __forceinline__ float hi2f(unsigned int u) {
  FU x; x.u = u & 0xffff0000u; return x.f;
}
__device__ __forceinline__ float lo2f(unsigned int u) {
  FU x; x.u = u << 16; return x.f;
}
__device__ __forceinline__ f32x2 pair2f(unsigned int u) {
  f32x2 r; r.x = lo2f(u); r.y = hi2f(u); return r;
}
__device__ __forceinline__ unsigned short f2b(float f) {
  bf16 h = __float2bfloat16(f);
  return *reinterpret_cast<unsigned short*>(&h);
}
__device__ __forceinline__ float gelu_f(float x) {
  return 0.5f * x * (1.0f + erff(x * 0.7071067811865475f));
}
__device__ __forceinline__ void stout(float* p, float v) { *p = v; }
__device__ __forceinline__ void stout(bf16* p, float v) { *p = __float2bfloat16(v); }

// ---------------- setup: LN1 (blocks 0..255) UNION weight prep (256..4355) --
__global__ __launch_bounds__(256) void setup_kernel(
    const float* __restrict__ x, const float* __restrict__ g,
    const float* __restrict__ bta,
    const float* __restrict__ q_w, const float* __restrict__ q_b,
    const float* __restrict__ k_w, const float* __restrict__ v_w,
    const float* __restrict__ pjw, const float* __restrict__ w1,
    const float* __restrict__ w2, const float* __restrict__ off4w,
    bf16* __restrict__ out, float* __restrict__ xnhwc,
    unsigned short* __restrict__ wqkv, float* __restrict__ bqkv,
    unsigned short* __restrict__ wproj, unsigned short* __restrict__ wmlp1,
    unsigned short* __restrict__ wmlp2, unsigned short* __restrict__ woff4i)
{
  __shared__ float s1[8][32], s2[8][32];
  __shared__ unsigned short tb[32][264];
  int bid = blockIdx.x;
  int t = threadIdx.x;
  if (bid < 256) {
    int pos = t & 31, cs = t >> 5;
    int p = bid * 32 + pos;
    int bb = p >> 12, hw = p & 4095;
    const float* xp = x + (size_t)bb * 256 * 4096 + hw;
    float vloc[32];
    float sum = 0.f, ss = 0.f;
#pragma unroll
    for (int i = 0; i < 32; ++i) {
      float v = xp[(size_t)(cs * 32 + i) * 4096];
      vloc[i] = v; sum += v; ss += v * v;
    }
    s1[cs][pos] = sum; s2[cs][pos] = ss;
    {
      float* xo = xnhwc + (size_t)p * 256 + cs * 32;
#pragma unroll
      for (int qd = 0; qd < 8; ++qd)
        *(float4*)(xo + qd * 4) = make_float4(vloc[qd*4], vloc[qd*4+1],
                                              vloc[qd*4+2], vloc[qd*4+3]);
    }
    __syncthreads();
    if (cs == 0) {
      float S = 0.f, Q = 0.f;
#pragma unroll
      for (int i = 0; i < 8; ++i) { S += s1[i][pos]; Q += s2[i][pos]; }
      float mu = S * (1.f / 256.f);
      float var = Q * (1.f / 256.f) - mu * mu;
      s1[0][pos] = mu;
      s2[0][pos] = rsqrtf(var + 1e-5f);
    }
    __syncthreads();
    float mu = s1[0][pos], rs = s2[0][pos];
#pragma unroll
    for (int i = 0; i < 32; ++i) {
      int c = cs * 32 + i;
      tb[pos][c] = f2b((vloc[i] - mu) * rs * g[c] + bta[c]);
    }
    __syncthreads();
    int px = t >> 3, grp = t & 7;
    bf16* op = out + ((size_t)bid * 32 + px) * 256 + grp * 32;
#pragma unroll
    for (int q = 0; q < 4; ++q)
      *(uint4*)(op + q * 8) = *(const uint4*)&tb[px][grp * 32 + q * 8];
  } else {
    int idx = (bid - 256) * 256 + t;
    const int S0 = 768 * 256;          // q|K|V weights, dezeroed
    const int S1 = S0 + 768;           // bias
    const int S2 = S1 + 256 * 256;
    const int S3 = S2 + 1024 * 256;
    const int S4 = S3 + 256 * 1024;
    const int S5 = S4 + 2048 * 128;
    if (idx < S0) {
      int n = idx >> 8, c = idx & 255;
      float v;
      if (n < 256)       v = q_w[n * 256 + c];
      else if (n < 512)  v = k_w[(n - 256) * 256 + c];
      else               v = v_w[(n - 512) * 256 + c];
      wqkv[idx] = f2b(v);
    } else if (idx < S1) {
      int n = idx - S0;
      bqkv[n] = (n < 256) ? q_b[n] : 0.f;
    } else if (idx < S2) {
      wproj[idx - S1] = f2b(pjw[idx - S1]);
    } else if (idx < S3) {
      wmlp1[idx - S2] = f2b(w1[idx - S2]);
    } else if (idx < S4) {
      wmlp2[idx - S3] = f2b(w2[idx - S3]);
    } else if (idx < S5) {
      int kk = idx - S4;
      int n = kk >> 7, c = kk & 127;
      // interleaved: n = 2r + coord  <-  off4w row coord*1024 + r
      woff4i[kk] = f2b(off4w[((size_t)((n & 1) * 1024 + (n >> 1))) * 128 + c]);
    }
  }
}

// ---------------- LN2: NHWC bf16 in -> NHWC bf16 out -----------------------
__global__ __launch_bounds__(256) void ln2_kernel(
    const bf16* __restrict__ xin, const float* __restrict__ g,
    const float* __restrict__ bta, bf16* __restrict__ out)
{
  __shared__ float sa[8][32], sb[8][32];
  __shared__ float mu_s[32], rs_s[32];
  int t = threadIdx.x;
  int px = t >> 3, grp = t & 7;
  size_t p = (size_t)blockIdx.x * 32 + px;
  const bf16* xp = xin + p * 256 + grp * 32;
  float v[32]; float sum = 0.f, ss = 0.f;
#pragma unroll
  for (int q = 0; q < 4; ++q) {
    U16x8 u; u.u4 = *(const uint4*)(xp + q * 8);
#pragma unroll
    for (int j = 0; j < 8; ++j) {
      float f = b2f(u.us[j]); v[q * 8 + j] = f; sum += f; ss += f * f;
    }
  }
  sa[grp][px] = sum; sb[grp][px] = ss;
  __syncthreads();
  if (t < 32) {
    float S = 0.f, Q = 0.f;
#pragma unroll
    for (int i = 0; i < 8; ++i) { S += sa[i][t]; Q += sb[i][t]; }
    float mu = S * (1.f / 256.f);
    mu_s[t] = mu;
    rs_s[t] = rsqrtf(Q * (1.f / 256.f) - mu * mu + 1e-5f);
  }
  __syncthreads();
  float mu = mu_s[px], rs = rs_s[px];
  bf16* op = out + p * 256 + grp * 32;
#pragma unroll
  for (int q = 0; q < 4; ++q) {
    U16x8 o;
#pragma unroll
    for (int j = 0; j < 8; ++j) {
      int c = grp * 32 + q * 8 + j;
      o.us[j] = f2b((v[q * 8 + j] - mu) * rs * g[c] + bta[c]);
    }
    *(uint4*)(op + q * 8) = o.u4;
  }
}

// ---------------- MFMA GEMM (NHWC): out[p][o] = sum_c A[p][c] W[o][c] ------
// OUTM: 0 bf16 NHWC; 1 f32 NCHW via LDS transpose (BN=64 only); 4 grouped-
//       QKV; 5 offset-grid head + coord pack (out=goff, res=gwt).
// RESM: 0 none; 1 f32 NHWC; 2 bf16 NHWC. ACT: 1 exact GELU.
template<int OUTM, int RESM, int ACT, int BM, int BN>
__global__ __launch_bounds__(256) void mgemm_kernel(
    const bf16* __restrict__ A, const unsigned short* __restrict__ Bw,
    const float* __restrict__ bias, const void* __restrict__ res,
    void* __restrict__ out, int N, int K, int lda, int ldb)
{
  constexpr int MT = BM / 32;
  constexpr int WNT = BN / 32;
  constexpr int AB_BYTES = (BM + BN) * 72 * 2;
  constexpr int T_LD = BM + 5;
  constexpr int T_BYTES = 64 * T_LD * 4;
  constexpr int SH_BYTES = (OUTM == 1 && T_BYTES > AB_BYTES) ? T_BYTES : AB_BYTES;
  __shared__ __attribute__((aligned(16))) char shraw[SH_BYTES];
  auto As = reinterpret_cast<unsigned short(*)[72]>(shraw);
  auto Bs = reinterpret_cast<unsigned short(*)[72]>(shraw + BM * 72 * 2);
  float (*T)[T_LD] = reinterpret_cast<float(*)[T_LD]>(shraw);

  int t = threadIdx.x;
  int m0 = blockIdx.y * BM, n0 = blockIdx.x * BN;
  int lane = t & 63, w = t >> 6;
  int l15 = lane & 15, quad = lane >> 4;
  int wm = (w >> 1) * (BM / 2), wn = (w & 1) * (BN / 2);
  f32x4 acc[MT][WNT];
#pragma unroll
  for (int mt = 0; mt < MT; ++mt)
#pragma unroll
    for (int nt = 0; nt < WNT; ++nt) acc[mt][nt] = (f32x4){0.f, 0.f, 0.f, 0.f};

  for (int k0 = 0; k0 < K; k0 += 64) {
#pragma unroll
    for (int i = 0; i < MT; ++i) {
      int idx = t + i * 256;
      int m = idx >> 3, oc = (idx & 7) * 8;
      *(uint4*)&As[m][oc] = *(const uint4*)(A + (size_t)(m0 + m) * lda + k0 + oc);
    }
#pragma unroll
    for (int i = 0; i < WNT; ++i) {
      int idx = t + i * 256;
      int n = idx >> 3, oc = (idx & 7) * 8;
      *(uint4*)&Bs[n][oc] = *(const uint4*)(Bw + (size_t)(n0 + n) * ldb + k0 + oc);
    }
    __syncthreads();
#pragma unroll
    for (int ks = 0; ks < 2; ++ks) {
      bf16x8 af[MT], bfr[WNT];
#pragma unroll
      for (int mt = 0; mt < MT; ++mt)
        af[mt] = __builtin_bit_cast(bf16x8,
            *(const uint4*)&As[wm + mt * 16 + l15][ks * 32 + quad * 8]);
#pragma unroll
      for (int nt = 0; nt < WNT; ++nt)
        bfr[nt] = __builtin_bit_cast(bf16x8,
            *(const uint4*)&Bs[wn + nt * 16 + l15][ks * 32 + quad * 8]);
#pragma unroll
      for (int mt = 0; mt < MT; ++mt)
#pragma unroll
        for (int nt = 0; nt < WNT; ++nt)
          acc[mt][nt] = __builtin_amdgcn_mfma_f32_16x16x32_bf16(
              af[mt], bfr[nt], acc[mt][nt], 0, 0, 0);
    }
    __syncthreads();
  }
  float bv[WNT];
#pragma unroll
  for (int nt = 0; nt < WNT; ++nt)
    bv[nt] = bias ? bias[n0 + wn + nt * 16 + l15] : 0.f;
#pragma unroll
  for (int mt = 0; mt < MT; ++mt) {
#pragma unroll
    for (int nt = 0; nt < WNT; ++nt) {
#pragma unroll
      for (int reg = 0; reg < 4; ++reg) {
        int m = m0 + wm + mt * 16 + quad * 4 + reg;
        int n = n0 + wn + nt * 16 + l15;
        float v = acc[mt][nt][reg] + bv[nt];
        if constexpr (ACT == 1) v = gelu_f(v);
        if constexpr (RESM == 1)
          v += ((const float*)res)[(size_t)m * N + n];
        if constexpr (RESM == 2)
          v += b2f(((const unsigned short*)res)[(size_t)m * N + n]);
        if constexpr (OUTM == 0)
          ((unsigned short*)out)[(size_t)m * N + n] = f2b(v);
        if constexpr (OUTM == 1)
          T[(n - n0)][(m - m0)] = v;
        if constexpr (OUTM == 4)
          ((unsigned short*)out)[((size_t)(n >> 8) * 8192 + m) * 256 + (n & 255)] = f2b(v);
        if constexpr (OUTM == 5) {
          float val = tanhf(v) * (2.0f / 64.0f);
          int r = n >> 1, coord = n & 1;
          int rc = coord ? (r & 31) : (r >> 5);
          float ref = rc * (4.0f / 63.0f) - 1.0f;
          float pix = (val + ref + 1.0f) * 31.5f;
          float other = __shfl_xor(pix, 1, 64);
          if (coord == 0) {
            float rowp = pix, colp = other;
            float r0f = floorf(rowp), c0f = floorf(colp);
            float wr = rowp - r0f, wc = colp - c0f;
            int r0 = (int)r0f, c0 = (int)c0f;
            bool rv0 = ((unsigned)r0 < 64u), rv1 = ((unsigned)(r0 + 1) < 64u);
            bool cv0 = ((unsigned)c0 < 64u), cv1 = ((unsigned)(c0 + 1) < 64u);
            float4 w4;
            w4.x = (rv0 && cv0) ? (1.f - wr) * (1.f - wc) : 0.f;
            w4.y = (rv0 && cv1) ? (1.f - wr) * wc : 0.f;
            w4.z = (rv1 && cv0) ? wr * (1.f - wc) : 0.f;
            w4.w = (rv1 && cv1) ? wr * wc : 0.f;
            ((int*)out)[(size_t)m * 1024 + r] = r0 * 64 + c0;
            *(float4*)((float*)res + ((size_t)m * 1024 + r) * 4) = w4;
          }
        }
      }
    }
  }
  if constexpr (OUTM == 1) {
    __syncthreads();
    constexpr int SEGS = BM / 32;
    int units = 64 * SEGS;
    if (t < units) {
      int nl = t / SEGS, seg = t % SEGS;
      int bI = m0 >> 12, hw0 = m0 & 4095;
      float* op = (float*)out + ((size_t)bI * 256 + n0 + nl) * 4096 + hw0 + seg * 32;
#pragma unroll
      for (int k = 0; k < 32; ++k) op[k] = T[nl][seg * 32 + k];
    }
  }
}

// ---------------- depthwise 3x3 stride-2 pad-1 conv, NHWC-128 --------------
template<typename TI, typename TO, int IC>
__global__ __launch_bounds__(256) void dwconv_kernel(
    const TI* __restrict__ in, const float* __restrict__ wgt,
    TO* __restrict__ out, int Hi, int Wi, int Ho, int Wo, int fuse,
    const float* __restrict__ bg_, const float* __restrict__ bb_,
    const float* __restrict__ bm_, const float* __restrict__ bv_)
{
  int idx = blockIdx.x * 256 + threadIdx.x;
  int c = idx & 127;
  int pp = idx >> 7;
  int ow = pp % Wo, oh = (pp / Wo) % Ho, bgi = pp / (Wo * Ho);
  const TI* ip;
  if constexpr (IC == 256)
    ip = in + ((size_t)(bgi >> 1) * 4096) * 256 + (bgi & 1) * 128 + c;
  else
    ip = in + ((size_t)bgi * Hi * Wi) * 128 + c;
  float acc = 0.f;
#pragma unroll
  for (int ky = 0; ky < 3; ++ky) {
    int ih = oh * 2 - 1 + ky;
    if ((unsigned)ih >= (unsigned)Hi) continue;
#pragma unroll
    for (int kx = 0; kx < 3; ++kx) {
      int iw = ow * 2 - 1 + kx;
      if ((unsigned)iw >= (unsigned)Wi) continue;
      acc += wgt[c * 9 + ky * 3 + kx] * cvt(ip[(size_t)(ih * Wi + iw) * IC]);
    }
  }
  if (fuse) {
    acc = (acc - bm_[c]) * rsqrtf(bv_[c] + 1e-5f) * bg_[c] + bb_[c];
    acc = gelu_f(acc);
  }
  stout(out + idx, acc);
}

// ---------------- r23: fused deformable attention (in-kernel gather) -------
// r22 structure; combine vectorized to float2 (v_pk_fma_f32), ks stride 36.
__global__ __launch_bounds__(256) void attn4_kernel(
    const bf16* __restrict__ qbuf, const unsigned short* __restrict__ Kimg,
    const unsigned short* __restrict__ Vimg, const int* __restrict__ goff,
    const float* __restrict__ gwt, const float* __restrict__ vbv,
    const float* __restrict__ pe, bf16* __restrict__ aout)
{
  __shared__ unsigned short ks[2][64][36];
  __shared__ unsigned short vs[2][32][72];
  __shared__ unsigned short PsQs[64][72];
  __shared__ unsigned short pesb[70][72];

  const float LOG2E = 1.4426950408889634f;
  int blk = blockIdx.x;
  int b = blk & 1, head = (blk >> 1) & 7, nw = blk >> 4;
  int wh = nw >> 3, ww = nw & 7;
  int t = threadIdx.x;
  int lane = t & 63, w = t >> 6;
  int l15 = lane & 15, quad = lane >> 4;
  int qc0 = head * 32;
  int g = head >> 2;                       // this head's offset group
  int gr_r = t >> 2, gr_seg = t & 3;
  int choff = qc0 + gr_seg * 8;
  size_t cb0 = ((size_t)(b * 2 + g) * 64 + nw) * 1024 + gr_r;
  size_t pbK = (size_t)b * 4096 * 256 + choff;

  uint4 kc[4], vc[4];
  f32x4 wv;
  auto gather = [&](int rc0) {
    size_t cbase = cb0 + rc0;
    int base = goff[cbase];
    wv = *(const f32x4*)(gwt + cbase * 4);
    int o00 = min(max(base, 0), 4095);
    int o01 = min(max(base + 1, 0), 4095);
    int o10 = min(max(base + 64, 0), 4095);
    int o11 = min(max(base + 65, 0), 4095);
    kc[0] = *(const uint4*)(Kimg + pbK + (size_t)o00 * 256);
    kc[1] = *(const uint4*)(Kimg + pbK + (size_t)o01 * 256);
    kc[2] = *(const uint4*)(Kimg + pbK + (size_t)o10 * 256);
    kc[3] = *(const uint4*)(Kimg + pbK + (size_t)o11 * 256);
    vc[0] = *(const uint4*)(Vimg + pbK + (size_t)o00 * 256);
    vc[1] = *(const uint4*)(Vimg + pbK + (size_t)o01 * 256);
    vc[2] = *(const uint4*)(Vimg + pbK + (size_t)o10 * 256);
    vc[3] = *(const uint4*)(Vimg + pbK + (size_t)o11 * 256);
  };
  auto combine = [&](int buf) {
    f32x2 aK[4], aV[4];
#pragma unroll
    for (int j = 0; j < 4; ++j) {
      aK[j] = (f32x2){0.f, 0.f};
      aV[j] = (f32x2){0.f, 0.f};
    }
#pragma unroll
    for (int c4 = 0; c4 < 4; ++c4) {
      U16x8 ku, vu; ku.u4 = kc[c4]; vu.u4 = vc[c4];
      f32x2 w2 = (f32x2){wv[c4], wv[c4]};
#pragma unroll
      for (int j = 0; j < 4; ++j) {
        aK[j] += w2 * pair2f(ku.uw[j]);   // v_pk_fma_f32
        aV[j] += w2 * pair2f(vu.uw[j]);
      }
    }
    U16x8 ok;
#pragma unroll
    for (int j = 0; j < 4; ++j) {
      ok.us[2 * j]     = f2b(aK[j].x);
      ok.us[2 * j + 1] = f2b(aK[j].y);
    }
    *(uint4*)&ks[buf][gr_r][gr_seg * 8] = ok.u4;
#pragma unroll
    for (int j = 0; j < 4; ++j) {
      int r0 = gr_seg * 8 + 2 * j;
      int r1 = r0 + 1;
      vs[buf][r0][gr_r ^ (((r0 >> 3) & 3) * 8)] = f2b(aV[j].x);
      vs[buf][r1][gr_r ^ (((r1 >> 3) & 3) * 8)] = f2b(aV[j].y);
    }
  };

  {
    int qt = t >> 2, oct = t & 3;
    int h = wh * 8 + (qt >> 3), wcol = ww * 8 + (qt & 7);
    const bf16* src = qbuf + ((size_t)b * 4096 + h * 64 + wcol) * 256 + qc0 + oct * 8;
    U16x8 u; u.u4 = *(const uint4*)src;
    U16x8 o;
#pragma unroll
    for (int j = 0; j < 8; ++j) o.us[j] = f2b(b2f(u.us[j]) * (0.0625f * LOG2E));
    *(uint4*)&PsQs[qt][oct * 8] = o.u4;
  }
  int ry0 = 56 - wh * 8, rx0 = 56 - ww * 8;
  for (int i = t; i < 70 * 70; i += 256) {
    int yy = i / 70, xx = i % 70;
    pesb[yy][xx] = f2b(pe[(size_t)head * 16129 + (ry0 + yy) * 127 + rx0 + xx] * LOG2E);
  }
  gather(0);
  combine(0);
  __syncthreads();

  bf16x8 aQ = __builtin_bit_cast(bf16x8, *(const uint4*)&PsQs[w * 16 + l15][quad * 8]);
  float l[4] = {0.f, 0.f, 0.f, 0.f};
  f32x4 oacc[2];
  oacc[0] = (f32x4){0.f, 0.f, 0.f, 0.f};
  oacc[1] = (f32x4){0.f, 0.f, 0.f, 0.f};

  int rowbase = 7 - (w * 2 + (quad >> 1));      // + 4*c + 2*(nt>>1)
  int Cb = 2 * l15 + 7 - (quad & 1) * 4;        // + (nt&1)*32; cols C-3..C

  for (int c = 0; c < 16; ++c) {
    int cur = c & 1;
    if (c) __syncthreads();
    if (c < 15) gather(c * 64 + 64);   // issue next tile's corner loads early

    f32x4 s[4];
    __builtin_amdgcn_s_setprio(1);
#pragma unroll
    for (int nt = 0; nt < 4; ++nt) {
      uint4 u = *(const uint4*)&ks[cur][nt * 16 + l15][quad * 8];
      bf16x8 bK = __builtin_bit_cast(bf16x8, u);
      f32x4 z = (f32x4){0.f, 0.f, 0.f, 0.f};
      s[nt] = __builtin_amdgcn_mfma_f32_16x16x32_bf16(aQ, bK, z, 0, 0, 0);
    }
    __builtin_amdgcn_s_setprio(0);
#pragma unroll
    for (int nt = 0; nt < 4; ++nt) {
      int row = rowbase + 4 * c + 2 * (nt >> 1);
      int C = Cb + (nt & 1) * 32;
      const unsigned int* pr = (const unsigned int*)&pesb[row][0];
      unsigned int pa = pr[(C - 3) >> 1];   // cols C-3 (lo), C-2 (hi)
      unsigned int pbm = pr[(C - 1) >> 1];  // cols C-1 (lo), C   (hi)
      s[nt][0] += hi2f(pbm);
      s[nt][1] += lo2f(pbm);
      s[nt][2] += hi2f(pa);
      s[nt][3] += lo2f(pa);
    }
#pragma unroll
    for (int reg = 0; reg < 4; ++reg) {
      float ps = 0.f;
#pragma unroll
      for (int nt = 0; nt < 4; ++nt) {
        float p = exp2f(s[nt][reg]);
        PsQs[w * 16 + quad * 4 + reg][nt * 16 + l15] = f2b(p);
        ps += p;
      }
      l[reg] += ps;   // cross-lane reduction deferred to after the loop
    }
    __builtin_amdgcn_s_setprio(1);
#pragma unroll
    for (int kst = 0; kst < 2; ++kst) {
      uint4 up = *(const uint4*)&PsQs[w * 16 + l15][kst * 32 + quad * 8];
      bf16x8 pA = __builtin_bit_cast(bf16x8, up);
#pragma unroll
      for (int nt2 = 0; nt2 < 2; ++nt2) {
        int row = nt2 * 16 + l15;
        int cbase = (kst * 32 + quad * 8) ^ (((row >> 3) & 3) * 8);
        uint4 uv = *(const uint4*)&vs[cur][row][cbase];
        bf16x8 vB = __builtin_bit_cast(bf16x8, uv);
        oacc[nt2] = __builtin_amdgcn_mfma_f32_16x16x32_bf16(pA, vB, oacc[nt2], 0, 0, 0);
      }
    }
    __builtin_amdgcn_s_setprio(0);
    if (c < 15) combine(cur ^ 1);
  }
#pragma unroll
  for (int reg = 0; reg < 4; ++reg) {
    l[reg] += __shfl_xor(l[reg], 1, 64);
    l[reg] += __shfl_xor(l[reg], 2, 64);
    l[reg] += __shfl_xor(l[reg], 4, 64);
    l[reg] += __shfl_xor(l[reg], 8, 64);
  }
#pragma unroll
  for (int nt2 = 0; nt2 < 2; ++nt2) {
    float vbias = vbv[qc0 + nt2 * 16 + l15];
#pragma unroll
    for (int reg = 0; reg < 4; ++reg) {
      int q = w * 16 + quad * 4 + reg;
      size_t p = (size_t)b * 4096 + (wh * 8 + (q >> 3)) * 64 + ww * 8 + (q & 7);
      aout[p * 256 + qc0 + nt2 * 16 + l15] =
          __float2bfloat16(oacc[nt2][reg] / l[reg] + vbias);
    }
  }
}

// ---------------------------------------------------------------------------
extern "C" void kernel_launch(void* const* d_in, const int* in_sizes, int n_in,
                              void* d_out, int out_size, void* d_ws, size_t ws_size,
                              hipStream_t stream) {
  (void)in_sizes; (void)n_in; (void)out_size; (void)ws_size;
  const float* x     = (const float*)d_in[0];
  const float* ln1g  = (const float*)d_in[1];
  const float* ln1b  = (const float*)d_in[2];
  const float* q_w   = (const float*)d_in[3];
  const float* q_b   = (const float*)d_in[4];
  const float* k_w   = (const float*)d_in[5];
  const float* k_b   = (const float*)d_in[6];
  const float* v_w   = (const float*)d_in[7];
  const float* v_b   = (const float*)d_in[8];
  const float* off1w = (const float*)d_in[9];
  const float* off2w = (const float*)d_in[10];
  const float* off3w = (const float*)d_in[11];
  const float* bng   = (const float*)d_in[12];
  const float* bnb   = (const float*)d_in[13];
  const float* bnm   = (const float*)d_in[14];
  const float* bnv   = (const float*)d_in[15];
  const float* off4w = (const float*)d_in[16];
  const float* pe    = (const float*)d_in[17];
  const float* pjw   = (const float*)d_in[18];
  const float* pjb   = (const float*)d_in[19];
  const float* ln2g  = (const float*)d_in[20];
  const float* ln2b  = (const float*)d_in[21];
  const float* w1    = (const float*)d_in[22];
  const float* b1    = (const float*)d_in[23];
  const float* w2    = (const float*)d_in[24];
  const float* b2    = (const float*)d_in[25];
  (void)k_b;
  float* outp = (float*)d_out;

  char* W = (char*)d_ws;
  bf16*  xa    = (bf16*) (W + 0);          // [8192][256]; reused as aout/xm
  float* dw1   = (float*)(W + 8388608);    // [4][1024][128] f32
  float* dw2   = (float*)(W + 10485760);   // [4][256][128] f32
  bf16*  dw3b  = (bf16*) (W + 11010048);   // [4][64][128] bf16
  bf16*  qkv   = (bf16*) (W + 13238272);   // [3][8192][256] (q|K|V, dezeroed)
  bf16*  qb    = qkv;
  bf16*  Kimg  = qkv + 2097152;            // [2][4096][256]
  bf16*  Vimg  = qkv + 2 * 2097152;        // [2][4096][256]
  bf16*  x2    = (bf16*) (W + 34209792);
  float* xnhwc = (float*)(W + 38404096);
  unsigned short* wqkv   = (unsigned short*)(W + 46792704);
  float*          bqkv   = (float*)         (W + 47448064);
  unsigned short* wproj  = (unsigned short*)(W + 47453184);
  unsigned short* wmlp1  = (unsigned short*)(W + 47584256);
  unsigned short* wmlp2  = (unsigned short*)(W + 48108544);
  unsigned short* woff4i = (unsigned short*)(W + 48632832);
  int*   goff  = (int*)  (W + 49157120);
  float* gwt   = (float*)(W + 50205696);   // ends at 54,400,000
  bf16*  aout = xa;
  bf16*  xm   = xa;
  bf16*  hdn  = Kimg;                      // [8192][1024] bf16, after attn done

  // 1. setup: LN1 + all weight prep in one launch
  setup_kernel<<<4356, 256, 0, stream>>>(
      x, ln1g, ln1b, q_w, q_b, k_w, v_w, pjw, w1, w2, off4w,
      xa, xnhwc, wqkv, bqkv, wproj, wmlp1, wmlp2, woff4i);
  // 2. fused QKV GEMM: N=768 -> q | Kimg | Vimg (dezeroed)
  mgemm_kernel<4, 0, 0, 128, 64><<<dim3(12, 64), 256, 0, stream>>>(
      xa, wqkv, bqkv, nullptr, qkv, 768, 256, 256, 256);
  // 3. offset branch: three parallel depthwise launches
  dwconv_kernel<bf16, float, 256><<<2048, 256, 0, stream>>>(
      qb, off1w, dw1, 64, 64, 32, 32, 0, nullptr, nullptr, nullptr, nullptr);
  dwconv_kernel<float, float, 128><<<512, 256, 0, stream>>>(
      dw1, off2w, dw2, 32, 32, 16, 16, 0, nullptr, nullptr, nullptr, nullptr);
  dwconv_kernel<float, bf16, 128><<<128, 256, 0, stream>>>(
      dw2, off3w, dw3b, 16, 16, 8, 8, 1, bng, bnb, bnm, bnv);
  // 4. offset head GEMM + tanh/grid + coord pack (OUTM=5, BM=64)
  mgemm_kernel<5, 0, 0, 64, 64><<<dim3(32, 4), 256, 0, stream>>>(
      dw3b, woff4i, nullptr, (const void*)gwt, goff, 2048, 128, 128, 128);
  // 5. fused deformable attention (in-kernel gather, no Ks/Vs round trip)
  attn4_kernel<<<1024, 256, 0, stream>>>(
      qb, (const unsigned short*)Kimg, (const unsigned short*)Vimg,
      goff, gwt, v_b, pe, aout);
  // 6. proj + residual(x_nhwc f32) -> x2 NHWC bf16
  mgemm_kernel<0, 1, 0, 64, 64><<<dim3(4, 128), 256, 0, stream>>>(
      aout, wproj, pjb, (const void*)xnhwc, x2, 256, 256, 256, 256);
  // 7. LN2 -> xm
  ln2_kernel<<<256, 256, 0, stream>>>(x2, ln2g, ln2b, xm);
  // 8. MLP1 + GELU -> hdn
  mgemm_kernel<0, 0, 1, 128, 64><<<dim3(16, 64), 256, 0, stream>>>(
      xm, wmlp1, b1, nullptr, hdn, 1024, 256, 256, 256);
  // 9. MLP2 + residual(x2) -> f32 NCHW d_out via LDS transpose
  mgemm_kernel<1, 2, 0, 64, 64><<<dim3(4, 128), 256, 0, stream>>>(
      hdn, wmlp2, b2, (const void*)x2, outp, 256, 1024, 1024, 1024);
}